// Round 13
// baseline (749.574 us; speedup 1.0000x reference)
//
#include <hip/hip_runtime.h>
#include <stdint.h>

#define B_ 4096
#define T_ 49
#define H_ 512
#define BT_ (B_*T_)
#define PB_ (T_*H_)          // ushorts per ping-pong buffer (25088; 50176 B)

typedef __bf16 bf16x8 __attribute__((ext_vector_type(8)));
typedef float  f32x4  __attribute__((ext_vector_type(4)));
typedef unsigned short ushort_;

__device__ __forceinline__ ushort_ f2bf(float f){
  unsigned int u = __float_as_uint(f);
  u += 0x7fffu + ((u >> 16) & 1u);           // RNE
  return (ushort_)(u >> 16);
}
__device__ __forceinline__ float fast_tanh(float x){
  float e = __expf(2.0f * x);
  return 1.0f - 2.0f * __builtin_amdgcn_rcpf(e + 1.0f);
}

// k_pack3: all three weights -> fragment-ordered bf16 in one launch.
__global__ __launch_bounds__(256) void k_pack3(
    const float* __restrict__ Wv, const float* __restrict__ Wh,
    const float* __restrict__ Ws, ushort_* __restrict__ bpack,
    ushort_* __restrict__ whp, ushort_* __restrict__ wsp){
  const int grp = blockIdx.x >> 7;            // 0,1,2
  const float* W = (grp==0) ? Wv : (grp==1) ? Wh : Ws;
  ushort_* pack  = (grp==0) ? bpack : (grp==1) ? whp : wsp;
  int idx = (blockIdx.x & 127) * 256 + threadIdx.x;   // 0..32767
  int lane = idx & 63;
  int gt   = (idx >> 6) & 31;
  int kk   = idx >> 11;
  int col  = gt*16 + (lane & 15);
  int k0   = kk*32 + (lane >> 4)*8;
  ushort4 lo, hi;
  lo.x = f2bf(W[(k0+0)*H_ + col]);
  lo.y = f2bf(W[(k0+1)*H_ + col]);
  lo.z = f2bf(W[(k0+2)*H_ + col]);
  lo.w = f2bf(W[(k0+3)*H_ + col]);
  hi.x = f2bf(W[(k0+4)*H_ + col]);
  hi.y = f2bf(W[(k0+5)*H_ + col]);
  hi.z = f2bf(W[(k0+6)*H_ + col]);
  hi.w = f2bf(W[(k0+7)*H_ + col]);
  ushort4* dst = (ushort4*)pack;
  dst[idx*2]   = lo;
  dst[idx*2+1] = hi;
}

// k_proj2 (MFMA): 16 batches/block; h@W_h and s@W_s; epilogue hpb & beta.
__global__ __launch_bounds__(256) void k_proj2(
    const float* __restrict__ h, const float* __restrict__ s,
    const ushort_* __restrict__ whp, const ushort_* __restrict__ wsp,
    const float* __restrict__ bh, const float* __restrict__ bs,
    const float* __restrict__ bv, const float* __restrict__ wbeta,
    const float* __restrict__ bbeta_p,
    float* __restrict__ hpb, float* __restrict__ beta)
{
  __shared__ __align__(16) ushort_ hl[16*H_];   // 16KB, A-frag order
  __shared__ __align__(16) ushort_ sl[16*H_];
  __shared__ float zwp[4][16];
  const int tid = threadIdx.x;
  const int w = tid >> 6, lane = tid & 63;
  const int l15 = lane & 15, l4 = lane >> 4;
  const int b0 = blockIdx.x * 16;

  {
    const int r = tid >> 4;
    const float4* hsrc = (const float4*)(h + (size_t)(b0+r)*H_);
    const float4* ssrc = (const float4*)(s + (size_t)(b0+r)*H_);
    #pragma unroll
    for(int p=0;p<8;p++){
      int q  = (tid & 15) + p*16;         // float4 col
      int k0 = q*4;
      float4 fh = hsrc[q];
      float4 fs = ssrc[q];
      int idx = (k0>>5)*512 + ((((k0&31)>>3)<<4) + r)*8 + (k0&7);
      ushort4 uh; uh.x=f2bf(fh.x); uh.y=f2bf(fh.y); uh.z=f2bf(fh.z); uh.w=f2bf(fh.w);
      ushort4 us; us.x=f2bf(fs.x); us.y=f2bf(fs.y); us.z=f2bf(fs.z); us.w=f2bf(fs.w);
      *(ushort4*)&hl[idx] = uh;
      *(ushort4*)&sl[idx] = us;
    }
  }
  __syncthreads();

  const bf16x8* __restrict__ bph = (const bf16x8*)whp;
  const bf16x8* __restrict__ bps = (const bf16x8*)wsp;
  const int bbase = w*512 + lane;

  f32x4 acch[8], accs[8];
  #pragma unroll
  for(int ni=0;ni<8;ni++){ acch[ni]=(f32x4){0,0,0,0}; accs[ni]=(f32x4){0,0,0,0}; }

  #pragma unroll 2
  for(int kk=0;kk<16;kk++){
    bf16x8 ah = *(const bf16x8*)&hl[kk*512 + lane*8];
    bf16x8 as2 = *(const bf16x8*)&sl[kk*512 + lane*8];
    #pragma unroll
    for(int ni=0;ni<8;ni++){
      acch[ni] = __builtin_amdgcn_mfma_f32_16x16x32_bf16(ah,  bph[kk*2048 + bbase + ni*64], acch[ni], 0,0,0);
      accs[ni] = __builtin_amdgcn_mfma_f32_16x16x32_bf16(as2, bps[kk*2048 + bbase + ni*64], accs[ni], 0,0,0);
    }
  }

  float bhv[8], bsv[8], bvv[8], wbv[8];
  #pragma unroll
  for(int ni=0;ni<8;ni++){
    int col = w*128 + ni*16 + l15;
    bhv[ni] = bh[col]; bsv[ni] = bs[col]; bvv[ni] = bv[col]; wbv[ni] = wbeta[col];
  }
  float btsum[4];
  #pragma unroll
  for(int rr=0;rr<4;rr++){
    int row = l4*4 + rr;
    float bsum = 0.f;
    #pragma unroll
    for(int ni=0;ni<8;ni++){
      int col = w*128 + ni*16 + l15;
      float hp = acch[ni][rr] + bhv[ni];
      hpb[(size_t)(b0+row)*H_ + col] = hp + bvv[ni];
      float bt = fast_tanh((accs[ni][rr] + bsv[ni] + hp) * 0.70710678118654752f);
      bsum = fmaf(bt, wbv[ni], bsum);
    }
    btsum[rr] = bsum;
  }
  #pragma unroll
  for(int rr=0;rr<4;rr++){
    btsum[rr] += __shfl_xor(btsum[rr], 1);
    btsum[rr] += __shfl_xor(btsum[rr], 2);
    btsum[rr] += __shfl_xor(btsum[rr], 4);
    btsum[rr] += __shfl_xor(btsum[rr], 8);
    if(l15 == 0) zwp[w][l4*4+rr] = btsum[rr];
  }
  __syncthreads();
  if(tid < 16)
    beta[b0+tid] = zwp[0][tid] + zwp[1][tid] + zwp[2][tid] + zwp[3][tid] + bbeta_p[0];
}

// k_fused (wave-specialized persistent): 256 blocks x 384 thr (6 waves).
// Waves 0-3 = consumers: r6's 2-pass GEMM (B depth-3 from L2, A dist-1 LDS)
// + z/softmax/PV. Waves 4-5 = producers: stage batch bi+1 into ping-pong LDS.
// vmcnt is per-wave -> stage-HBM stream and B-L2 stream never interact (r7's
// false-drain impossible). Producer regs ~56, consumer ~205 -> no spill.
__global__ __launch_bounds__(384, 1) void k_fused(
    const float* __restrict__ v, const ushort_* __restrict__ bpack,
    const float* __restrict__ hpb, const float* __restrict__ wz,
    const float* __restrict__ bz_p, const float* __restrict__ beta,
    const float* __restrict__ s, float* __restrict__ out)
{
  __shared__ __align__(16) ushort_ Av[2*PB_];   // 100352 B
  __shared__ float zw[4][64];
  __shared__ float a_s[64];
  const int tid = threadIdx.x;
  const int blk = blockIdx.x;                   // 0..255
  const bool cons = (tid < 256);
  const int w = tid >> 6, lane = tid & 63;
  const int l15 = lane & 15, l4 = lane >> 4;
  const int pt = tid - 256;                     // producer col 0..127

  const bf16x8* __restrict__ bp = (const bf16x8*)bpack;
  const int bbase = w*256 + lane;               // + kk*2048 + p*1024 + ni*64

  float wzv0[4], wzv1[4];
  if(cons){
    #pragma unroll
    for(int ni=0;ni<4;ni++){
      wzv0[ni] = wz[      w*64 + ni*16 + l15];
      wzv1[ni] = wz[256 + w*64 + ni*16 + l15];
    }
  }
  const float bzv = bz_p[0];

  // producer: stage one 49x512 f32 batch -> swizzled bf16 LDS buffer.
  // 128 threads; thread pt covers float4-column pt of every row. 7 bursts x 7
  // rows, dist-1 (load burst g+1 before writing burst g).
#define PWB(ROW) ((ROW)*1024 + ((((pt)>>1) ^ ((ROW)&7))<<4) + (((pt)&1)<<3))
#define PLOAD(R, G) { \
    _Pragma("unroll") \
    for(int q=0;q<7;q++) R[q] = __builtin_nontemporal_load(vv + ((G)*7+q)*128 + pt); }
#define PWRITE(R, G, DST) { \
    _Pragma("unroll") \
    for(int q=0;q<7;q++){ \
      ushort4 u_; u_.x=f2bf(R[q][0]); u_.y=f2bf(R[q][1]); \
      u_.z=f2bf(R[q][2]); u_.w=f2bf(R[q][3]); \
      *(ushort4*)((DST) + PWB((G)*7+q)) = u_; } }
#define PSTAGE(DST, BSRC) { \
    const f32x4* vv = (const f32x4*)(v + (size_t)(BSRC)*T_*H_); \
    f32x4 rA[7], rB[7]; \
    PLOAD(rA, 0) \
    PLOAD(rB, 1) PWRITE(rA, 0, DST) \
    PLOAD(rA, 2) PWRITE(rB, 1, DST) \
    PLOAD(rB, 3) PWRITE(rA, 2, DST) \
    PLOAD(rA, 4) PWRITE(rB, 3, DST) \
    PLOAD(rB, 5) PWRITE(rA, 4, DST) \
    PLOAD(rA, 6) PWRITE(rB, 5, DST) \
    PWRITE(rA, 6, DST) }

#define AFRAG(af, KS, SRC) { \
    _Pragma("unroll") \
    for(int mi=0;mi<4;mi++){ \
      int row_ = (mi < 3) ? (mi*16 + l15) : 48; \
      int g_   = ((KS)*4 + l4) ^ (row_ & 7); \
      af[mi] = *(const bf16x8*)((SRC) + row_*1024 + (g_<<4)); } }
#define MFMA16(af, bfr) { \
    _Pragma("unroll") \
    for(int mi=0;mi<4;mi++) \
      _Pragma("unroll") \
      for(int ni=0;ni<4;ni++) \
        acc[mi][ni] = __builtin_amdgcn_mfma_f32_16x16x32_bf16(af[mi], bfr[ni], acc[mi][ni], 0,0,0); }
#define BLOADP(DST, KK, P) { \
    _Pragma("unroll") \
    for(int ni=0;ni<4;ni++) DST[ni] = bp[(KK)*2048 + (P)*1024 + bbase + ni*64]; }

  // one N-pass (16 K-steps), acc[4][4]; B depth-3, A dist-1.
#define GPASS(P, SRC) { \
    BLOADP(bq[0], 0, P) BLOADP(bq[1], 1, P) BLOADP(bq[2], 2, P) \
    AFRAG(af2[0], 0, SRC) \
    _Pragma("unroll") \
    for(int kk=0; kk<16; kk++){ \
      if(kk < 15){ AFRAG(af2[(kk+1)&1], kk+1, SRC) } \
      MFMA16(af2[kk&1], bq[kk%3]) \
      if(kk < 13){ BLOADP(bq[kk%3], kk+3, P) } \
    } }

#define ZPART(WZV, COFF, OP) { \
    float hpv[4]; \
    _Pragma("unroll") \
    for(int ni=0;ni<4;ni++) hpv[ni] = hpb[(size_t)b*H_ + (COFF) + w*64 + ni*16 + l15]; \
    float zp[16]; \
    _Pragma("unroll") \
    for(int mi=0;mi<4;mi++) \
      _Pragma("unroll") \
      for(int r=0;r<4;r++){ \
        float az = 0.f; \
        _Pragma("unroll") \
        for(int ni=0;ni<4;ni++) \
          az = fmaf(fast_tanh(acc[mi][ni][r] + hpv[ni]), WZV[ni], az); \
        zp[mi*4+r] = az; \
      } \
    _Pragma("unroll") \
    for(int i=0;i<16;i++){ \
      zp[i] += __shfl_xor(zp[i], 1); \
      zp[i] += __shfl_xor(zp[i], 2); \
      zp[i] += __shfl_xor(zp[i], 4); \
      zp[i] += __shfl_xor(zp[i], 8); \
    } \
    if(l15 == 0){ \
      _Pragma("unroll") \
      for(int mi=0;mi<4;mi++) \
        _Pragma("unroll") \
        for(int r=0;r<4;r++) \
          zw[w][mi*16 + l4*4 + r] OP zp[mi*4+r]; \
    } }

  // ---- prologue: producers stage batch blk*16 into buf 0
  if(!cons){ PSTAGE((char*)Av, blk*16) }
  __syncthreads();

  #pragma unroll 1
  for(int bi=0; bi<16; bi++){
    const int b = blk*16 + bi;
    const char* curc = (const char*)Av + (bi&1)*(PB_*2);
    char* nxtc = (char*)Av + ((bi+1)&1)*(PB_*2);

    if(!cons){
      if(bi < 15){ PSTAGE(nxtc, b+1) }
    } else {
      f32x4 acc[4][4];
      bf16x8 bq[3][4], af2[2][4];

      #pragma unroll
      for(int mi=0;mi<4;mi++)
        #pragma unroll
        for(int ni=0;ni<4;ni++) acc[mi][ni] = (f32x4){0.f,0.f,0.f,0.f};
      GPASS(0, curc)
      ZPART(wzv0, 0, =)

      #pragma unroll
      for(int mi=0;mi<4;mi++)
        #pragma unroll
        for(int ni=0;ni<4;ni++) acc[mi][ni] = (f32x4){0.f,0.f,0.f,0.f};
      GPASS(1, curc)
      ZPART(wzv1, 256, +=)
    }
    __syncthreads();                 // zw ready; stage of bi+1 complete

    if(tid < 64){
      float zv;
      if(tid < T_)       zv = zw[0][tid] + zw[1][tid] + zw[2][tid] + zw[3][tid] + bzv;
      else if(tid == T_) zv = beta[b];
      else               zv = -3.0e38f;
      float m = zv;
      #pragma unroll
      for(int off=32;off>=1;off>>=1) m = fmaxf(m, __shfl_xor(m, off));
      float e = (tid <= T_) ? __expf(zv - m) : 0.f;
      float ssum = e;
      #pragma unroll
      for(int off=32;off>=1;off>>=1) ssum += __shfl_xor(ssum, off);
      a_s[tid] = e * __builtin_amdgcn_rcpf(ssum);
    }
    __syncthreads();                 // a_s ready

    if(cons){
      const int n0 = tid * 2;
      float ax = 0.f, ay = 0.f;
      #pragma unroll 7
      for(int t=0;t<T_;t++){
        float at = a_s[t];
        unsigned int u = *(const unsigned int*)(curc + t*1024
                           + ((((n0>>3) ^ (t&7)))<<4) + ((n0&7)<<1));
        ax = fmaf(at, __uint_as_float((u & 0xFFFFu) << 16), ax);
        ay = fmaf(at, __uint_as_float(u & 0xFFFF0000u), ay);
      }
      float a49 = a_s[T_];
      float2 sv = ((const float2*)(s + (size_t)b*H_))[tid];
      ax = fmaf(a49, sv.x, ax);
      ay = fmaf(a49, sv.y, ay);
      float2 res; res.x = ax; res.y = ay;
      ((float2*)(out + (size_t)b*H_))[tid] = res;
    }
    __syncthreads();                 // PV done reading curc before producers reuse it
  }
}

extern "C" void kernel_launch(void* const* d_in, const int* in_sizes, int n_in,
                              void* d_out, int out_size, void* d_ws, size_t ws_size,
                              hipStream_t stream)
{
  const float* v   = (const float*)d_in[0];
  const float* h   = (const float*)d_in[1];
  const float* s   = (const float*)d_in[2];
  const float* Wh  = (const float*)d_in[3];
  const float* bh  = (const float*)d_in[4];
  const float* Wv  = (const float*)d_in[5];
  const float* bv  = (const float*)d_in[6];
  const float* wz  = (const float*)d_in[7];
  const float* bz  = (const float*)d_in[8];
  const float* Ws  = (const float*)d_in[9];
  const float* bs  = (const float*)d_in[10];
  const float* wb  = (const float*)d_in[11];
  const float* bbet= (const float*)d_in[12];
  float* out = (float*)d_out;

  float* hpb  = (float*)d_ws;                      // B*H f32
  float* beta = hpb + (size_t)B_*H_;               // B f32
  ushort_* bpack = (ushort_*)(beta + B_);          // Wv frag-packed bf16
  ushort_* whp   = bpack + (size_t)H_*H_;          // Wh frag-packed
  ushort_* wsp   = whp   + (size_t)H_*H_;          // Ws frag-packed

  k_pack3<<<384, 256, 0, stream>>>(Wv, Wh, Ws, bpack, whp, wsp);
  k_proj2<<<B_/16, 256, 0, stream>>>(h, s, whp, wsp, bh, bs, bv, wb, bbet, hpb, beta);
  k_fused<<<256, 384, 0, stream>>>(v, bpack, hpb, wz, bz, beta, s, out);
}

// Round 14
// 284.359 us; speedup vs baseline: 2.6360x; 2.6360x over previous
//
#include <hip/hip_runtime.h>
#include <stdint.h>

#define B_ 4096
#define T_ 49
#define H_ 512
#define BT_ (B_*T_)

typedef __bf16 bf16x8 __attribute__((ext_vector_type(8)));
typedef float  f32x4  __attribute__((ext_vector_type(4)));
typedef unsigned short ushort_;

__device__ __forceinline__ ushort_ f2bf(float f){
  unsigned int u = __float_as_uint(f);
  u += 0x7fffu + ((u >> 16) & 1u);           // RNE
  return (ushort_)(u >> 16);
}
__device__ __forceinline__ float fast_tanh(float x){
  float e = __expf(2.0f * x);
  return 1.0f - 2.0f * __builtin_amdgcn_rcpf(e + 1.0f);
}

// k_pack3: all three weights -> fragment-ordered bf16 in one launch.
__global__ __launch_bounds__(256) void k_pack3(
    const float* __restrict__ Wv, const float* __restrict__ Wh,
    const float* __restrict__ Ws, ushort_* __restrict__ bpack,
    ushort_* __restrict__ whp, ushort_* __restrict__ wsp){
  const int grp = blockIdx.x >> 7;            // 0,1,2
  const float* W = (grp==0) ? Wv : (grp==1) ? Wh : Ws;
  ushort_* pack  = (grp==0) ? bpack : (grp==1) ? whp : wsp;
  int idx = (blockIdx.x & 127) * 256 + threadIdx.x;   // 0..32767
  int lane = idx & 63;
  int gt   = (idx >> 6) & 31;
  int kk   = idx >> 11;
  int col  = gt*16 + (lane & 15);
  int k0   = kk*32 + (lane >> 4)*8;
  ushort4 lo, hi;
  lo.x = f2bf(W[(k0+0)*H_ + col]);
  lo.y = f2bf(W[(k0+1)*H_ + col]);
  lo.z = f2bf(W[(k0+2)*H_ + col]);
  lo.w = f2bf(W[(k0+3)*H_ + col]);
  hi.x = f2bf(W[(k0+4)*H_ + col]);
  hi.y = f2bf(W[(k0+5)*H_ + col]);
  hi.z = f2bf(W[(k0+6)*H_ + col]);
  hi.w = f2bf(W[(k0+7)*H_ + col]);
  ushort4* dst = (ushort4*)pack;
  dst[idx*2]   = lo;
  dst[idx*2+1] = hi;
}

// k_proj2 (MFMA): 16 batches/block; h@W_h and s@W_s; epilogue hpb & beta.
__global__ __launch_bounds__(256) void k_proj2(
    const float* __restrict__ h, const float* __restrict__ s,
    const ushort_* __restrict__ whp, const ushort_* __restrict__ wsp,
    const float* __restrict__ bh, const float* __restrict__ bs,
    const float* __restrict__ bv, const float* __restrict__ wbeta,
    const float* __restrict__ bbeta_p,
    float* __restrict__ hpb, float* __restrict__ beta)
{
  __shared__ __align__(16) ushort_ hl[16*H_];   // 16KB, A-frag order
  __shared__ __align__(16) ushort_ sl[16*H_];
  __shared__ float zwp[4][16];
  const int tid = threadIdx.x;
  const int w = tid >> 6, lane = tid & 63;
  const int l15 = lane & 15, l4 = lane >> 4;
  const int b0 = blockIdx.x * 16;

  {
    const int r = tid >> 4;
    const float4* hsrc = (const float4*)(h + (size_t)(b0+r)*H_);
    const float4* ssrc = (const float4*)(s + (size_t)(b0+r)*H_);
    #pragma unroll
    for(int p=0;p<8;p++){
      int q  = (tid & 15) + p*16;         // float4 col
      int k0 = q*4;
      float4 fh = hsrc[q];
      float4 fs = ssrc[q];
      int idx = (k0>>5)*512 + ((((k0&31)>>3)<<4) + r)*8 + (k0&7);
      ushort4 uh; uh.x=f2bf(fh.x); uh.y=f2bf(fh.y); uh.z=f2bf(fh.z); uh.w=f2bf(fh.w);
      ushort4 us; us.x=f2bf(fs.x); us.y=f2bf(fs.y); us.z=f2bf(fs.z); us.w=f2bf(fs.w);
      *(ushort4*)&hl[idx] = uh;
      *(ushort4*)&sl[idx] = us;
    }
  }
  __syncthreads();

  const bf16x8* __restrict__ bph = (const bf16x8*)whp;
  const bf16x8* __restrict__ bps = (const bf16x8*)wsp;
  const int bbase = w*512 + lane;

  f32x4 acch[8], accs[8];
  #pragma unroll
  for(int ni=0;ni<8;ni++){ acch[ni]=(f32x4){0,0,0,0}; accs[ni]=(f32x4){0,0,0,0}; }

  #pragma unroll 2
  for(int kk=0;kk<16;kk++){
    bf16x8 ah = *(const bf16x8*)&hl[kk*512 + lane*8];
    bf16x8 as2 = *(const bf16x8*)&sl[kk*512 + lane*8];
    #pragma unroll
    for(int ni=0;ni<8;ni++){
      acch[ni] = __builtin_amdgcn_mfma_f32_16x16x32_bf16(ah,  bph[kk*2048 + bbase + ni*64], acch[ni], 0,0,0);
      accs[ni] = __builtin_amdgcn_mfma_f32_16x16x32_bf16(as2, bps[kk*2048 + bbase + ni*64], accs[ni], 0,0,0);
    }
  }

  float bhv[8], bsv[8], bvv[8], wbv[8];
  #pragma unroll
  for(int ni=0;ni<8;ni++){
    int col = w*128 + ni*16 + l15;
    bhv[ni] = bh[col]; bsv[ni] = bs[col]; bvv[ni] = bv[col]; wbv[ni] = wbeta[col];
  }
  float btsum[4];
  #pragma unroll
  for(int rr=0;rr<4;rr++){
    int row = l4*4 + rr;
    float bsum = 0.f;
    #pragma unroll
    for(int ni=0;ni<8;ni++){
      int col = w*128 + ni*16 + l15;
      float hp = acch[ni][rr] + bhv[ni];
      hpb[(size_t)(b0+row)*H_ + col] = hp + bvv[ni];
      float bt = fast_tanh((accs[ni][rr] + bsv[ni] + hp) * 0.70710678118654752f);
      bsum = fmaf(bt, wbv[ni], bsum);
    }
    btsum[rr] = bsum;
  }
  #pragma unroll
  for(int rr=0;rr<4;rr++){
    btsum[rr] += __shfl_xor(btsum[rr], 1);
    btsum[rr] += __shfl_xor(btsum[rr], 2);
    btsum[rr] += __shfl_xor(btsum[rr], 4);
    btsum[rr] += __shfl_xor(btsum[rr], 8);
    if(l15 == 0) zwp[w][l4*4+rr] = btsum[rr];
  }
  __syncthreads();
  if(tid < 16)
    beta[b0+tid] = zwp[0][tid] + zwp[1][tid] + zwp[2][tid] + zwp[3][tid] + bbeta_p[0];
}

// k_fused (M=98): one block per BATCH PAIR (2048 blocks x 256 thr). Halves the
// B-frag L2 stream (one 512KB bpack read serves 2 batches). r6-style chunk
// interleave; B loads for chunk c issued in chunk c-1 BEFORE that chunk's
// v-loads (no false vmcnt drains). acc[7][4]; rows 98-111 are never-stored
// LDS garbage (MFMA rows independent; unused rows never read back).
__global__ __launch_bounds__(256, 1) void k_fused(
    const float* __restrict__ v, const ushort_* __restrict__ bpack,
    const float* __restrict__ hpb, const float* __restrict__ wz,
    const float* __restrict__ bz_p, const float* __restrict__ beta,
    const float* __restrict__ s, float* __restrict__ out)
{
  __shared__ __align__(16) ushort_ Av[112*512];   // 114688 B
  __shared__ float zw[2][4][64];
  __shared__ float a_s[2][64];
  const int tid = threadIdx.x;
  const int w = tid >> 6, lane = tid & 63;
  const int l15 = lane & 15, l4 = lane >> 4;
  const int b0 = blockIdx.x * 2;

  const f32x4* __restrict__ vsrc4 = (const f32x4*)(v + (size_t)b0 * T_ * H_); // 98x128
  const bf16x8* __restrict__ bp = (const bf16x8*)bpack;
  const int bbase = w*256 + lane;            // + kk*2048 + p*1024 + ni*64
  const bool j6ok = (tid < 32);
  const float bzv = bz_p[0];

#define SMAP(J, ROW, C4) { int flat_ = ((J)<6)? (tid + (J)*256) : (1536 + tid); \
                           ROW = flat_>>4; C4 = flat_&15; }
#define VLOAD7(R, CH) { \
    _Pragma("unroll") \
    for(int j=0;j<7;j++){ if(j<6 || j6ok){ int r_,c_; SMAP(j,r_,c_) \
      R[j] = __builtin_nontemporal_load(vsrc4 + r_*128 + (CH)*16 + c_); } } }
#define SWRITE7(R, CH) { \
    _Pragma("unroll") \
    for(int j=0;j<7;j++){ if(j<6 || j6ok){ int r_,c_; SMAP(j,r_,c_) \
      int g_ = (((CH)*8 + (c_>>1)) ^ (r_&7)); \
      ushort4 u_; u_.x=f2bf(R[j][0]); u_.y=f2bf(R[j][1]); \
      u_.z=f2bf(R[j][2]); u_.w=f2bf(R[j][3]); \
      *(ushort4*)((char*)Av + r_*1024 + (g_<<4) + ((c_&1)<<3)) = u_; } } }
#define AFRAG7(af, KS) { \
    _Pragma("unroll") \
    for(int mi=0;mi<7;mi++){ \
      int row_ = mi*16 + l15; \
      int g_   = ((KS)*4 + l4) ^ (row_ & 7); \
      af[mi] = *(const bf16x8*)((const char*)Av + row_*1024 + (g_<<4)); } }
#define MFMA28(af, bfr) { \
    _Pragma("unroll") \
    for(int mi=0;mi<7;mi++) \
      _Pragma("unroll") \
      for(int ni=0;ni<4;ni++) \
        acc[mi][ni] = __builtin_amdgcn_mfma_f32_16x16x32_bf16(af[mi], bfr[ni], acc[mi][ni], 0,0,0); }
#define BLOADP(DST, KK, P) { \
    _Pragma("unroll") \
    for(int ni=0;ni<4;ni++) DST[ni] = bp[(KK)*2048 + (P)*1024 + bbase + ni*64]; }

  f32x4 nf[7];
  f32x4 acc[7][4];
  bf16x8 ba[4], bb[4], af[7];

  // ---- prologue: stage chunk 0; B(0),B(1) issued before barrier
  VLOAD7(nf, 0)
  SWRITE7(nf, 0)
  #pragma unroll
  for(int mi=0;mi<7;mi++)
    #pragma unroll
    for(int ni=0;ni<4;ni++) acc[mi][ni] = (f32x4){0.f,0.f,0.f,0.f};
  BLOADP(ba, 0, 0)
  BLOADP(bb, 1, 0)
  __syncthreads();

  // ---- pass 0: cols 0..255, 8 chunks x 2 K-steps; staging interleaved
  #pragma unroll 1
  for(int c=0;c<8;c++){
    if(c<7){ VLOAD7(nf, c+1) }
    AFRAG7(af, 2*c)
    MFMA28(af, ba)
    if(c<7){ BLOADP(ba, 2*c+2, 0) }
    AFRAG7(af, 2*c+1)
    MFMA28(af, bb)
    if(c<7){ BLOADP(bb, 2*c+3, 0) }
    if(c<7){ SWRITE7(nf, c+1) }
    __syncthreads();
  }

  // ---- pass-0 z-partials (cols w*64..)
#define ZPART(COFF, OP) { \
    float hpv0[4], hpv1[4], wzv[4]; \
    _Pragma("unroll") \
    for(int ni=0;ni<4;ni++){ \
      int col = (COFF) + w*64 + ni*16 + l15; \
      wzv[ni]  = wz[col]; \
      hpv0[ni] = hpb[(size_t)b0*H_ + col]; \
      hpv1[ni] = hpb[(size_t)(b0+1)*H_ + col]; \
    } \
    float zp[28]; \
    _Pragma("unroll") \
    for(int mi=0;mi<7;mi++) \
      _Pragma("unroll") \
      for(int r=0;r<4;r++){ \
        int rowl = mi*16 + l4*4 + r; \
        float az = 0.f; \
        _Pragma("unroll") \
        for(int ni=0;ni<4;ni++){ \
          float hp = (rowl >= 49) ? hpv1[ni] : hpv0[ni]; \
          az = fmaf(fast_tanh(acc[mi][ni][r] + hp), wzv[ni], az); \
        } \
        zp[mi*4+r] = az; \
      } \
    _Pragma("unroll") \
    for(int i=0;i<28;i++){ \
      zp[i] += __shfl_xor(zp[i], 1); \
      zp[i] += __shfl_xor(zp[i], 2); \
      zp[i] += __shfl_xor(zp[i], 4); \
      zp[i] += __shfl_xor(zp[i], 8); \
    } \
    if(l15 == 0){ \
      _Pragma("unroll") \
      for(int mi=0;mi<7;mi++) \
        _Pragma("unroll") \
        for(int r=0;r<4;r++){ \
          int rowl = mi*16 + l4*4 + r; \
          if(rowl < 98){ \
            int isb1 = (rowl >= 49); \
            zw[isb1][w][rowl - (isb1 ? 49 : 0)] OP zp[mi*4+r]; \
          } \
        } \
    } }

  ZPART(0, =)

  // ---- pass 1: cols 256..511, pure GEMM from staged LDS
  #pragma unroll
  for(int mi=0;mi<7;mi++)
    #pragma unroll
    for(int ni=0;ni<4;ni++) acc[mi][ni] = (f32x4){0.f,0.f,0.f,0.f};
  BLOADP(ba, 0, 1)
  BLOADP(bb, 1, 1)
  #pragma unroll 1
  for(int kk=0; kk<16; kk+=2){
    AFRAG7(af, kk)
    MFMA28(af, ba)
    if(kk<14){ BLOADP(ba, kk+2, 1) }
    AFRAG7(af, kk+1)
    MFMA28(af, bb)
    if(kk<14){ BLOADP(bb, kk+3, 1) }
  }

  ZPART(256, +=)
  __syncthreads();

  // ---- softmax: wave 0 -> batch b0, wave 1 -> batch b0+1
  if(tid < 128){
    const int bb3 = tid >> 6, t = tid & 63;
    float zv;
    if(t < T_)       zv = zw[bb3][0][t] + zw[bb3][1][t] + zw[bb3][2][t] + zw[bb3][3][t] + bzv;
    else if(t == T_) zv = beta[b0 + bb3];
    else             zv = -3.0e38f;
    float m = zv;
    #pragma unroll
    for(int off=32;off>=1;off>>=1) m = fmaxf(m, __shfl_xor(m, off));
    float e = (t <= T_) ? __expf(zv - m) : 0.f;
    float ssum = e;
    #pragma unroll
    for(int off=32;off>=1;off>>=1) ssum += __shfl_xor(ssum, off);
    a_s[bb3][t] = e * __builtin_amdgcn_rcpf(ssum);
  }
  __syncthreads();

  // ---- PV: both batches, 2 cols/thread
  {
    const int n0 = tid * 2;
    #pragma unroll
    for(int bb4=0; bb4<2; bb4++){
      float ax = 0.f, ay = 0.f;
      #pragma unroll 7
      for(int t=0;t<T_;t++){
        float at = a_s[bb4][t];
        int row = bb4*49 + t;
        unsigned int u = *(const unsigned int*)((const char*)Av + row*1024
                           + ((((n0>>3) ^ (row&7)))<<4) + ((n0&7)<<1));
        ax = fmaf(at, __uint_as_float((u & 0xFFFFu) << 16), ax);
        ay = fmaf(at, __uint_as_float(u & 0xFFFF0000u), ay);
      }
      float a49 = a_s[bb4][T_];
      float2 sv = ((const float2*)(s + (size_t)(b0+bb4)*H_))[tid];
      ax = fmaf(a49, sv.x, ax);
      ay = fmaf(a49, sv.y, ay);
      float2 res; res.x = ax; res.y = ay;
      ((float2*)(out + (size_t)(b0+bb4)*H_))[tid] = res;
    }
  }
}

extern "C" void kernel_launch(void* const* d_in, const int* in_sizes, int n_in,
                              void* d_out, int out_size, void* d_ws, size_t ws_size,
                              hipStream_t stream)
{
  const float* v   = (const float*)d_in[0];
  const float* h   = (const float*)d_in[1];
  const float* s   = (const float*)d_in[2];
  const float* Wh  = (const float*)d_in[3];
  const float* bh  = (const float*)d_in[4];
  const float* Wv  = (const float*)d_in[5];
  const float* bv  = (const float*)d_in[6];
  const float* wz  = (const float*)d_in[7];
  const float* bz  = (const float*)d_in[8];
  const float* Ws  = (const float*)d_in[9];
  const float* bs  = (const float*)d_in[10];
  const float* wb  = (const float*)d_in[11];
  const float* bbet= (const float*)d_in[12];
  float* out = (float*)d_out;

  float* hpb  = (float*)d_ws;                      // B*H f32
  float* beta = hpb + (size_t)B_*H_;               // B f32
  ushort_* bpack = (ushort_*)(beta + B_);          // Wv frag-packed bf16
  ushort_* whp   = bpack + (size_t)H_*H_;          // Wh frag-packed
  ushort_* wsp   = whp   + (size_t)H_*H_;          // Ws frag-packed

  k_pack3<<<384, 256, 0, stream>>>(Wv, Wh, Ws, bpack, whp, wsp);
  k_proj2<<<B_/16, 256, 0, stream>>>(h, s, whp, wsp, bh, bs, bv, wb, bbet, hpb, beta);
  k_fused<<<B_/2, 256, 0, stream>>>(v, bpack, hpb, wz, bz, beta, s, out);
}